// Round 8
// baseline (268.957 us; speedup 1.0000x reference)
//
#include <hip/hip_runtime.h>

// PlatonicConv: linear attention with tetrahedral-group RoPE.
// N=32768 nodes, C=E=384, G=12 groups, H=1, D=32, P=16, 64 graphs (batch sorted).
// I/O fp32; internal bf16 MFMA with fp32 accumulate.
//
// Round 8 (rocprof: kv_k 49.4us latency-bound - VALU 17%, occ 24%, LDS-issue floor):
//  - kv_k/attn_k inner loops read kbuf/qbuf rows as float4 (ds_read_b128 x8
//    instead of ds_read_b32 x32 per node): LDS pipe 186 -> ~96 cyc/node
//  - 1024 blocks x 32-node windows (was 512x64): ~24 waves/CU for latency hiding
// Pipeline (6 dispatches): memset KV, prep, gemm_qv, kv_k, attn_k, gemm_out.

#define N_NODES 32768
#define K_DIM   384
#define P_PAIR  16
#define NUM_GRAPHS 64

typedef unsigned short u16;
typedef __bf16 bf16x8 __attribute__((ext_vector_type(8)));
typedef float  f32x4  __attribute__((ext_vector_type(4)));
typedef __attribute__((address_space(3))) void       lds_void;
typedef const __attribute__((address_space(1))) void gbl_void;

__device__ __forceinline__ u16 f2bf(float f) {
    unsigned int i = __float_as_uint(f);
    unsigned int r = i + 0x7FFFu + ((i >> 16) & 1u);   // RNE
    return (u16)(r >> 16);
}
__device__ __forceinline__ float bf2f(u16 u) {
    union { unsigned int i; float f; } x;
    x.i = ((unsigned int)u) << 16;
    return x.f;
}

// ---------------------------------------------------------------------------
// prep: xb = bf16(x) (vectorized x8); WqvT[n][k]=[Wq|Wv][k][n]; WoT[n][k]=Wo[k][n]
__global__ void prep(const float* __restrict__ x,
                     const float* __restrict__ Wq, const float* __restrict__ Wv,
                     const float* __restrict__ Wo,
                     u16* __restrict__ xb, u16* __restrict__ WqvT,
                     u16* __restrict__ WoT) {
    int b = blockIdx.x;
    if (b < 6144) {                              // 6144*256*8 = 12,582,912 = N*384
        int i = (b * 256 + threadIdx.x) * 8;
        float4 a0 = *reinterpret_cast<const float4*>(x + i);
        float4 a1 = *reinterpret_cast<const float4*>(x + i + 4);
        union { u16 u[8]; float4 v; } pk;
        pk.u[0] = f2bf(a0.x); pk.u[1] = f2bf(a0.y);
        pk.u[2] = f2bf(a0.z); pk.u[3] = f2bf(a0.w);
        pk.u[4] = f2bf(a1.x); pk.u[5] = f2bf(a1.y);
        pk.u[6] = f2bf(a1.z); pk.u[7] = f2bf(a1.w);
        *reinterpret_cast<float4*>(xb + i) = pk.v;
    } else {
        int idx = (b - 6144) * 256 + threadIdx.x;    // < 442,368 (grid exact)
        if (idx < 294912) {
            int n = idx / 384, k = idx % 384;
            WqvT[idx] = f2bf(n < 384 ? Wq[k * 384 + n] : Wv[k * 384 + (n - 384)]);
        } else {
            int j = idx - 294912;
            int n = j / 384, k = j % 384;
            WoT[j] = f2bf(Wo[k * 384 + n]);
        }
    }
}

// ---------------------------------------------------------------------------
// Shared GEMM core: 128x128 tile, BK=32, glds width-16 staging into unpadded
// 128x32 bf16 LDS tiles (A at T[0:4096], B at T[4096:8192] u16), 4 waves 2x2,
// 4x4 16x16x32 MFMA. Staging: 16 segments of 1024B; lane l of segment s covers
// row s*16 + l/4, cols (l&3)*8 -> LDS offset exactly lane*16 B (glds order).
#define GEMM_CORE(A_PTR, B_PTR)                                                  \
    __shared__ __align__(1024) u16 T[8192];                                      \
    const int tid = threadIdx.x;                                                 \
    const int w = tid >> 6, lane = tid & 63;                                     \
    const int wr = (w >> 1) << 6, wc = (w & 1) << 6;                             \
    const int lm = lane & 15, q = lane >> 4;                                     \
    const int srow = lane >> 2, sc8 = (lane & 3) << 3;                           \
    f32x4 acc[4][4];                                                             \
    _Pragma("unroll") for (int i = 0; i < 4; i++)                                \
    _Pragma("unroll") for (int j = 0; j < 4; j++)                                \
    _Pragma("unroll") for (int r = 0; r < 4; r++) acc[i][j][r] = 0.0f;           \
    for (int k0 = 0; k0 < K_DIM; k0 += 32) {                                     \
        __syncthreads();                                                         \
        _Pragma("unroll")                                                        \
        for (int s = w; s < 16; s += 4) {                                        \
            int row = ((s & 7) << 4) + srow;                                     \
            const u16* gp = ((s >> 3) ? (B_PTR) + (size_t)(n0 + row) * K_DIM     \
                                      : (A_PTR) + (size_t)(m0 + row) * K_DIM)    \
                            + k0 + sc8;                                          \
            __builtin_amdgcn_global_load_lds((gbl_void*)gp,                      \
                                             (lds_void*)&T[s << 9], 16, 0, 0);   \
        }                                                                        \
        __syncthreads();                                                         \
        bf16x8 af[4], bfr[4];                                                    \
        _Pragma("unroll") for (int i = 0; i < 4; i++) {                          \
            af[i]  = *reinterpret_cast<const bf16x8*>(&T[(wr + i * 16 + lm) * 32 + q * 8]);          \
            bfr[i] = *reinterpret_cast<const bf16x8*>(&T[4096 + (wc + i * 16 + lm) * 32 + q * 8]);   \
        }                                                                        \
        _Pragma("unroll") for (int i = 0; i < 4; i++)                            \
        _Pragma("unroll") for (int j = 0; j < 4; j++)                            \
            acc[i][j] = __builtin_amdgcn_mfma_f32_16x16x32_bf16(af[i], bfr[j], acc[i][j], 0, 0, 0);  \
    }

// ---------------------------------------------------------------------------
// [Q|V] = xb @ [Wq|Wv]^T + [bq|bv].  Swizzle: XCD owns 32 row-tiles, bx fastest.
__global__ __launch_bounds__(256) void gemm_qv(
    const u16* __restrict__ A, const u16* __restrict__ Bt,
    const float* __restrict__ bq, const float* __restrict__ bv,
    u16* __restrict__ Qw, u16* __restrict__ Vd) {
    const int b = blockIdx.x;                 // 1536 blocks
    const int xcd = b & 7, jj = b >> 3;       // jj 0..191
    const int by = xcd * 32 + jj / 6, bx = jj % 6;
    const int m0 = by << 7, n0 = bx << 7;
    GEMM_CORE(A, Bt)
    // C/D layout: col = lane&15, row = (lane>>4)*4 + r  [HW-confirmed round-4 probe]
    u16* Cq = (n0 < 384) ? Qw : Vd;
    const float* bias = (n0 < 384) ? bq : bv;
    const int coff = (n0 < 384) ? 0 : 384;
#pragma unroll
    for (int j = 0; j < 4; j++) {
        int gc = n0 + wc + j * 16 + lm - coff;
        float bs = bias[gc];
#pragma unroll
        for (int i = 0; i < 4; i++) {
            int gr = m0 + wr + i * 16 + q * 4;
#pragma unroll
            for (int r = 0; r < 4; r++)
                Cq[(size_t)(gr + r) * 384 + gc] = f2bf(acc[i][j][r] + bs);
        }
    }
}

// ---------------------------------------------------------------------------
// out = O @ Wo^T + bo (fp32 out).  O = attn output, in-place over Qw.
__global__ __launch_bounds__(256) void gemm_out(
    const u16* __restrict__ A, const u16* __restrict__ Bt,
    const float* __restrict__ bias, float* __restrict__ Cmat) {
    const int b = blockIdx.x;                 // 768 blocks
    const int xcd = b & 7, jj = b >> 3;       // jj 0..95
    const int by = xcd * 32 + jj / 3, bx = jj % 3;
    const int m0 = by << 7, n0 = bx << 7;
    GEMM_CORE(A, Bt)
#pragma unroll
    for (int j = 0; j < 4; j++) {
        int gc = n0 + wc + j * 16 + lm;
        float bs = bias[gc];
#pragma unroll
        for (int i = 0; i < 4; i++) {
            int gr = m0 + wr + i * 16 + q * 4;
#pragma unroll
            for (int r = 0; r < 4; r++)
                Cmat[(size_t)(gr + r) * 384 + gc] = acc[i][j][r] + bs;
        }
    }
}

// ---------------------------------------------------------------------------
// KV[g][grp][d][e] += (1/512) sum_n k_d(n) v_e(n).  1024 blocks x 32 nodes,
// 384 threads = (grp, e). Flush accumulator (atomics) on graph change (sorted).
// kbuf rows read as float4 (ds_read_b128) to cut LDS-pipe issue pressure.
__global__ __launch_bounds__(384) void kv_k(
    const u16* __restrict__ V, const float* __restrict__ pos,
    const int* __restrict__ batch, const float* __restrict__ freqs,
    float* __restrict__ KV) {
    const int nb = blockIdx.x << 5;
    const int t = threadIdx.x;
    const int grp = t >> 5, ec = t & 31;
    const int p = ec >> 1, sgn = ec & 1;
    const float f0 = freqs[(grp * P_PAIR + p) * 3 + 0];
    const float f1 = freqs[(grp * P_PAIR + p) * 3 + 1];
    const float f2 = freqs[(grp * P_PAIR + p) * 3 + 2];

    __shared__ float kbuf[8][384];
    __shared__ int gbuf[8];
    f32x4 acc[8];
#pragma unroll
    for (int d = 0; d < 8; d++)
#pragma unroll
        for (int c = 0; c < 4; c++) acc[d][c] = 0.0f;
    int gcur = batch[nb];
    const float scale = 1.0f / 512.0f;

    for (int base = nb; base < nb + 32; base += 8) {
        __syncthreads();
        if (t < 8) gbuf[t] = batch[base + t];
#pragma unroll
        for (int i = 0; i < 8; i++) {
            int n = base + i;
            float ph = pos[n * 3 + 0] * f0 + pos[n * 3 + 1] * f1 + pos[n * 3 + 2] * f2;
            float sn, cs;
            __sincosf(ph, &sn, &cs);
            kbuf[i][t] = sgn ? (sn + cs) : (cs - sn);   // rope applied to ones
        }
        __syncthreads();
#pragma unroll
        for (int i = 0; i < 8; i++) {
            int g = gbuf[i];                            // block-uniform
            if (g != gcur) {
                float* dst = KV + ((gcur * 12 + grp) << 10) + ec;
#pragma unroll
                for (int d = 0; d < 8; d++)
#pragma unroll
                    for (int c = 0; c < 4; c++) {
                        atomicAdd(dst + ((d * 4 + c) << 5), acc[d][c] * scale);
                        acc[d][c] = 0.0f;
                    }
                gcur = g;
            }
            float vv = bf2f(V[(size_t)(base + i) * 384 + t]);
            const f32x4* kr = reinterpret_cast<const f32x4*>(&kbuf[i][grp << 5]);
#pragma unroll
            for (int d = 0; d < 8; d++) {
                f32x4 kk = kr[d];                       // ds_read_b128
#pragma unroll
                for (int c = 0; c < 4; c++) acc[d][c] = fmaf(kk[c], vv, acc[d][c]);
            }
        }
    }
    float* dst = KV + ((gcur * 12 + grp) << 10) + ec;
#pragma unroll
    for (int d = 0; d < 8; d++)
#pragma unroll
        for (int c = 0; c < 4; c++)
            atomicAdd(dst + ((d * 4 + c) << 5), acc[d][c] * scale);
}

// ---------------------------------------------------------------------------
// O[n][grp*32+e] = sum_d qrot[n][grp][d] * KV[batch[n]][grp][d][e].  In-place
// over Qw.  qbuf rows read as float4 (ds_read_b128).
__global__ __launch_bounds__(384) void attn_k(
    u16* __restrict__ Qw, const float* __restrict__ pos,
    const int* __restrict__ batch, const float* __restrict__ freqs,
    const float* __restrict__ KV) {
    const int nb = blockIdx.x << 5;
    const int t = threadIdx.x;
    const int grp = t >> 5, ec = t & 31;
    const int p = ec >> 1, sgn = ec & 1;
    const float f0 = freqs[(grp * P_PAIR + p) * 3 + 0];
    const float f1 = freqs[(grp * P_PAIR + p) * 3 + 1];
    const float f2 = freqs[(grp * P_PAIR + p) * 3 + 2];

    __shared__ float qbuf[8][384];
    __shared__ int gbuf[8];
    f32x4 kv[8];
    int gcur = -1;
    const int cq = t & ~1;

    for (int base = nb; base < nb + 32; base += 8) {
        __syncthreads();
        if (t < 8) gbuf[t] = batch[base + t];
#pragma unroll
        for (int i = 0; i < 8; i++) {
            int n = base + i;
            float qa = bf2f(Qw[(size_t)n * 384 + cq]);
            float qb = bf2f(Qw[(size_t)n * 384 + cq + 1]);
            float ph = pos[n * 3 + 0] * f0 + pos[n * 3 + 1] * f1 + pos[n * 3 + 2] * f2;
            float sn, cs;
            __sincosf(ph, &sn, &cs);
            qbuf[i][t] = sgn ? (qa * sn + qb * cs) : (qa * cs - qb * sn);
        }
        __syncthreads();
#pragma unroll
        for (int i = 0; i < 8; i++) {
            int g = gbuf[i];                            // block-uniform
            if (g != gcur) {
                gcur = g;
                const float* src = KV + ((g * 12 + grp) << 10) + ec;
#pragma unroll
                for (int d = 0; d < 8; d++)
#pragma unroll
                    for (int c = 0; c < 4; c++) kv[d][c] = src[((d * 4 + c) << 5)];
            }
            const f32x4* qr = reinterpret_cast<const f32x4*>(&qbuf[i][grp << 5]);
            float o = 0.0f;
#pragma unroll
            for (int d = 0; d < 8; d++) {
                f32x4 qq = qr[d];                       // ds_read_b128
#pragma unroll
                for (int c = 0; c < 4; c++) o = fmaf(qq[c], kv[d][c], o);
            }
            Qw[(size_t)(base + i) * 384 + t] = f2bf(o);
        }
    }
}

// ---------------------------------------------------------------------------
extern "C" void kernel_launch(void* const* d_in, const int* in_sizes, int n_in,
                              void* d_out, int out_size, void* d_ws, size_t ws_size,
                              hipStream_t stream) {
    const float* x     = (const float*)d_in[0];
    const float* pos   = (const float*)d_in[1];
    const int*   batch = (const int*)d_in[2];
    const float* Wq    = (const float*)d_in[3];
    const float* bq    = (const float*)d_in[4];
    const float* Wv    = (const float*)d_in[5];
    const float* bv    = (const float*)d_in[6];
    const float* Wo    = (const float*)d_in[7];
    const float* bo    = (const float*)d_in[8];
    const float* fr    = (const float*)d_in[9];
    float* out = (float*)d_out;

    char* ws = (char*)d_ws;                   // total use ~29.2 MB
    float* KV   = (float*)(ws);               //  3,145,728 B
    u16*   WqvT = (u16*)(ws + 3145728);       //    589,824 B
    u16*   WoT  = (u16*)(ws + 3735552);       //    294,912 B
    u16*   Qw   = (u16*)(ws + 4030464);       // 25,165,824 B (Q, then O in-place)
    // d_out (50.3 MB fp32) doubles as scratch until gemm_out overwrites it:
    u16*   Vd   = (u16*)d_out;                // [0, 25.2 MB): V bf16
    u16*   xb   = (u16*)d_out + N_NODES * 384;// [25.2, 50.3 MB): x as bf16

    hipMemsetAsync(KV, 0, (size_t)NUM_GRAPHS * 12 * 32 * 32 * sizeof(float), stream);
    prep<<<dim3(7872), dim3(256), 0, stream>>>(x, Wq, Wv, Wo, xb, WqvT, WoT);
    gemm_qv<<<dim3(1536), dim3(256), 0, stream>>>(xb, WqvT, bq, bv, Qw, Vd);
    kv_k<<<dim3(1024), dim3(384), 0, stream>>>(Vd, pos, batch, fr, KV);
    attn_k<<<dim3(1024), dim3(384), 0, stream>>>(Qw, pos, batch, fr, KV);
    gemm_out<<<dim3(768), dim3(256), 0, stream>>>(Qw, WoT, bo, out);
}